// Round 18
// baseline (157.083 us; speedup 1.0000x reference)
//
#include <hip/hip_runtime.h>
#include <hip/hip_bf16.h>
#include <math.h>

typedef __bf16 bf16t;
typedef __bf16 bf8v __attribute__((ext_vector_type(8)));
typedef float  f4v  __attribute__((ext_vector_type(4)));
typedef float  f16v __attribute__((ext_vector_type(16)));
typedef unsigned int u32;
typedef u32 u4v __attribute__((ext_vector_type(4)));

#define DD  4
#define FF  64
#define HH  128
#define FIN 129
#define MT  128   // rows per block; 32 rows per wave (one 32-col C tile)

#define AS1 __attribute__((address_space(1)))
#define AS3 __attribute__((address_space(3)))

// param LDS offsets (f32 elements). P_B2S holds b2 summed over d (b2 enters
// linearly before the post-sum LN, so Σ_d b2[d] folds into emb's C-init).
#define P_FREQS 0      // [4][64]
#define P_B1    256    // [4][128]
#define P_W1L   768    // [4][128]
#define P_G1    1280   // [4][128]
#define P_BB1   1792   // [4][128]
#define P_B2S   2304   // [128]
#define P_OG    2432   // [128]
#define P_OB    2560   // [128]
#define P_B3    2688   // [128]
#define P_TOT   2816   // 11.3 KB; total LDS = 64 KB (2 bufs) + 11.3 KB

// XOR-swizzled LDS index: element [row][k] of a row-major [*][128] bf16 tile,
// 16B chunk (k>>3) XORed with (row&7) -> spread banks for ds_read_b128.
__device__ __forceinline__ int swz(int row, int k) {
  return row * HH + ((((k >> 3) ^ (row & 7)) << 3) | (k & 7));
}

// Hidden-index permutation for CONTRACTION tiles (w2, w3), 32x32x16 version.
// C-layout (m74/m101): col=lane&31, row=(reg&3)+8*(reg>>2)+4*(lane>>5).
// B slot (half h=lane>>5, elem j) at k-step kk consumes staged k-row
// g = kk*16+8h+j. Staged g holding original hidden o = g with bits 2<->3
// swapped makes the B fragment equal the lane's own C registers -> ZERO
// cross-lane shuffles (involution).
__device__ __forceinline__ int hperm32(int k) {
  return (k & ~12) | ((k & 4) << 1) | ((k & 8) >> 1);
}

// ---- weight prep: f32 -> bf16, transposed to [n][k] for fragment loads ----
// SOURCE-indexed: thread i reads w{1,2,3}[i] COALESCED and scatter-writes the
// 2B bf16 transposed element (scattered stores are fire-and-forget).
__global__ void prep_weights(const float* __restrict__ w1,
                             const float* __restrict__ w2,
                             const float* __restrict__ w3,
                             bf16t* __restrict__ w1t,
                             bf16t* __restrict__ w2t,
                             bf16t* __restrict__ w3t,
                             float* __restrict__ w1last) {
  int i = blockIdx.x * blockDim.x + threadIdx.x;
  if (i < DD * FIN * HH) {           // 66048: w1 -> w1t (k<128) | w1last (k=128)
    int n = i & 127, dk = i >> 7, k = dk % FIN, d = dk / FIN;
    float v = w1[i];
    if (k == 128) w1last[d * HH + n] = v;
    else          w1t[(d * HH + n) * HH + k] = (bf16t)v;
  }
  if (i < DD * HH * HH) {            // 65536: w2 -> w2t (k hperm32'd dest)
    int n = i & 127, k = (i >> 7) & 127, d = i >> 14;
    w2t[(d * HH + n) * HH + hperm32(k)] = (bf16t)w2[i];
  }
  if (i < HH * HH) {                 // 16384: w3 -> w3t (k hperm32'd dest)
    int n = i & 127, k = i >> 7;
    w3t[n * HH + hperm32(k)] = (bf16t)w3[i];
  }
}

// Async stage of a 128x128 bf16 [n][k] tile into swizzled LDS via
// global_load_lds (width 16). LDS dest LINEAR; XOR swizzle applied to the
// GLOBAL source chunk. Exactly 8 VMEM ops per wave.
__device__ __forceinline__ void stage_w_async(const bf16t* __restrict__ w,
                                              bf16t* __restrict__ ldsW,
                                              int tid, int wave) {
  int g0 = (tid & ~15) | ((tid & 15) ^ ((tid >> 4) & 7));
  const bf16t* src = w + g0 * 8;            // 16B source chunk (permuted)
  bf16t* dst = ldsW + wave * 64 * 8;        // wave-uniform 16B-chunk base
  #pragma unroll
  for (int j = 0; j < 8; ++j) {
    __builtin_amdgcn_global_load_lds((const AS1 void*)(src + j * 2048),
                                     (AS3 void*)(dst + j * 2048), 16, 0, 0);
  }
}

__device__ __forceinline__ u32 pack2(float a, float b) {
  union { bf16t h; unsigned short u; } ua, ub;
  ua.h = (bf16t)a; ub.h = (bf16t)b;
  return ((u32)ub.u << 16) | (u32)ua.u;
}

// Build a bf8v from 8 f32 via whole-word packing (no 16-bit sub-register
// inserts — each element-wise bf16 vector write costs a hidden v_bfi/v_perm
// read-modify-write; u32 assembly lets the compiler emit v_cvt_pk_bf16_f32).
__device__ __forceinline__ bf8v pack8(const float* v) {
  u4v w;
  w.x = pack2(v[0], v[1]);
  w.y = pack2(v[2], v[3]);
  w.z = pack2(v[4], v[5]);
  w.w = pack2(v[6], v[7]);
  union { u4v w; bf8v v; } cv;
  cv.w = w;
  return cv.v;
}

// Shuffle-free B-fragment pack (companion of hperm32):
// bb[kk=2t+s] element j = h[tile t][reg j+8s].
__device__ __forceinline__ void pack_frag32(const f16v (&h)[4], bf8v (&bb)[8]) {
  #pragma unroll
  for (int t = 0; t < 4; ++t)
    #pragma unroll
    for (int s = 0; s < 2; ++s) {
      u4v wv;
      wv.x = pack2(h[t][8 * s + 0], h[t][8 * s + 1]);
      wv.y = pack2(h[t][8 * s + 2], h[t][8 * s + 3]);
      wv.z = pack2(h[t][8 * s + 4], h[t][8 * s + 5]);
      wv.w = pack2(h[t][8 * s + 6], h[t][8 * s + 7]);
      union { u4v w; bf8v v; } cv;
      cv.w = wv;
      bb[2 * t + s] = cv.v;
    }
}

// Drain-then-barrier. In this schedule each drain point has ONLY the wave's
// own 8 stage-loads outstanding, issued a full compute phase earlier -> the
// vmcnt(0) wait is ~free, and the barrier doubles as the WAR fence for the
// buffer restaged right after it (all waves past it have, by program order,
// finished the GEMM that read that buffer).
#define VM_SYNC0() do {                                        \
    asm volatile("s_waitcnt vmcnt(0)" ::: "memory");           \
    __builtin_amdgcn_s_barrier();                              \
  } while (0)

__launch_bounds__(256, 2)
__global__ void fourier_mlp(
    const float* __restrict__ cont,   // [N,4]
    const float* __restrict__ freqs,  // [4,64]
    const float* __restrict__ b1,     // [4,128]
    const float* __restrict__ ln1g,
    const float* __restrict__ ln1b,
    const float* __restrict__ b2,
    const float* __restrict__ outg,   // [128]
    const float* __restrict__ outb,
    const float* __restrict__ b3,
    const bf16t* __restrict__ w1t,    // [4][128][128] bf16, [d][n][k]
    const bf16t* __restrict__ w2t,    // [4][128][128] (k hperm32'd)
    const bf16t* __restrict__ w3t,    // [128][128]    (k hperm32'd)
    const float* __restrict__ w1last, // [4][128]
    float* __restrict__ out)          // [N,128] f32
{
  __shared__ __align__(16) bf16t ldsW0[HH * HH];  // 32 KB: w1[d] / w3
  __shared__ __align__(16) bf16t ldsW1[HH * HH];  // 32 KB: w2[d]
  __shared__ __align__(16) float ldsP[P_TOT];     // 11.3 KB: small params

  const int tid  = threadIdx.x;
  const int lane = tid & 63;
  const int wave = tid >> 6;        // 0..3
  const int l31  = lane & 31;       // C col = batch row within wave slab
  const int h    = lane >> 5;       // lane half
  const int h8   = h * 8;           // A/B k sub-range base
  const int h4   = h * 4;           // C row sub-offset
  const int rowbase = blockIdx.x * MT;
  const int wrow = wave * 32;       // wave's 32-row slab

  // ---- prologue: w1[0] -> ldsW0 (async), params -> ldsP, cont -> regs ----
  f4v call = *(const f4v*)&cont[(rowbase + wrow + l31) * DD];

  stage_w_async(w1t, ldsW0, tid, wave);
  ldsP[P_FREQS + tid] = freqs[tid];
  #pragma unroll
  for (int i = 0; i < 2; ++i) {
    int j = tid + i * 256;
    ldsP[P_B1 + j]  = b1[j];
    ldsP[P_W1L + j] = w1last[j];
    ldsP[P_G1 + j]  = ln1g[j];
    ldsP[P_BB1 + j] = ln1b[j];
  }
  if (tid < 128) {
    // b2 summed over d: enters linearly before the post-sum LN
    ldsP[P_B2S + tid] = b2[tid] + b2[HH + tid] + b2[2 * HH + tid] + b2[3 * HH + tid];
    ldsP[P_OG + tid] = outg[tid];
    ldsP[P_OB + tid] = outb[tid];
    ldsP[P_B3 + tid] = b3[tid];
  }

  __syncthreads();  // full drain once: w1[0] + params + cont all ready

  // emb C-init = b2sum (folds all four per-d b2 adds)
  f16v emb[4];
  #pragma unroll
  for (int t = 0; t < 4; ++t)
    #pragma unroll
    for (int a = 0; a < 4; ++a) {
      f4v b2s = *(const f4v*)&ldsP[P_B2S + t * 32 + a * 8 + h4];
      #pragma unroll
      for (int r = 0; r < 4; ++r) emb[t][a * 4 + r] = b2s[r];
    }

  for (int d = 0; d < DD; ++d) {
    const float c = call[d];

    // GEMM1 C-init = b1 + c*w1last (VALU-only; overlaps w1[d] staging)
    f16v acc[4];
    #pragma unroll
    for (int t = 0; t < 4; ++t)
      #pragma unroll
      for (int a = 0; a < 4; ++a) {
        f4v b1v = *(const f4v*)&ldsP[P_B1 + d * HH + t * 32 + a * 8 + h4];
        f4v w1l = *(const f4v*)&ldsP[P_W1L + d * HH + t * 32 + a * 8 + h4];
        #pragma unroll
        for (int r = 0; r < 4; ++r) acc[t][a * 4 + r] = b1v[r] + c * w1l[r];
      }

    // trig B-frags: fB[kk<4] = cos block, fB[4+kk2] = sin block.
    // Slot j at step kk, half h -> feature (kk&3)*16 + h8 + j.
    // f32 staging arrays + whole-word pack8 (no bf16 sub-element inserts).
    bf8v fB[8];
    #pragma unroll
    for (int k2 = 0; k2 < 4; ++k2) {
      f4v f0 = *(const f4v*)&ldsP[P_FREQS + d * FF + k2 * 16 + h8];
      f4v f1 = *(const f4v*)&ldsP[P_FREQS + d * FF + k2 * 16 + h8 + 4];
      float cs[8], sn[8];
      #pragma unroll
      for (int u = 0; u < 8; ++u) {
        float fv = (u < 4) ? f0[u] : f1[u - 4];
        float a = c * fv;
        float t = a - floorf(a);   // revolutions: sin/cos(2*pi*t)
        cs[u] = __builtin_amdgcn_cosf(t);
        sn[u] = __builtin_amdgcn_sinf(t);
      }
      fB[k2]     = pack8(cs);
      fB[4 + k2] = pack8(sn);
    }

    VM_SYNC0();  // A: w1[d] landed; all waves done GEMM2[d-1] (buf1 free)

    // w2[d] -> buf1 (WAR safe: barrier A implies GEMM2[d-1] complete).
    // Latency window = GEMM1 + epilogue.
    stage_w_async(w2t + d * HH * HH, ldsW1, tid, wave);

    // ===== GEMM1: acc[t] += w1t(A) * feat(B), reads buf0 =====
    #pragma unroll
    for (int kk = 0; kk < 8; ++kk)
      #pragma unroll
      for (int t = 0; t < 4; ++t) {
        bf8v wf = *(const bf8v*)&ldsW0[swz(t * 32 + l31, kk * 16 + h8)];
        acc[t] = __builtin_amdgcn_mfma_f32_32x32x16_bf16(wf, fB[kk], acc[t], 0, 0, 0);
      }

    // ===== epilogue: LN over hidden (bias already in acc), ReLU, pack =====
    bf8v bB[8];
    {
      float s = 0.0f, ss = 0.0f;
      #pragma unroll
      for (int t = 0; t < 4; ++t)
        #pragma unroll
        for (int x = 0; x < 16; ++x) {
          float v = acc[t][x];
          s += v; ss += v * v;
        }
      s  += __shfl_xor(s, 32);   // partner lane holds the other 16 rows/tile
      ss += __shfl_xor(ss, 32);
      float mu   = s * (1.0f / 128.0f);
      float var  = ss * (1.0f / 128.0f) - mu * mu;
      float rstd = rsqrtf(var + 1e-5f);
      #pragma unroll
      for (int t = 0; t < 4; ++t)
        #pragma unroll
        for (int a = 0; a < 4; ++a) {
          f4v gv = *(const f4v*)&ldsP[P_G1 + d * HH + t * 32 + a * 8 + h4];
          f4v bv = *(const f4v*)&ldsP[P_BB1 + d * HH + t * 32 + a * 8 + h4];
          #pragma unroll
          for (int r = 0; r < 4; ++r) {
            float v = (acc[t][a * 4 + r] - mu) * rstd * gv[r] + bv[r];
            acc[t][a * 4 + r] = fmaxf(v, 0.0f);
          }
        }
      pack_frag32(acc, bB);   // zero-shuffle (hperm32'd w2 compensates)
    }

    VM_SYNC0();  // B: w2[d] landed; all waves done GEMM1[d] (buf0 free)

    // next w1 (or w3) -> buf0 (WAR safe: barrier B implies GEMM1[d] complete).
    // Latency window = GEMM2 + next iteration's C-init/trig (or final LN).
    stage_w_async(d < 3 ? (w1t + (d + 1) * HH * HH) : w3t, ldsW0, tid, wave);

    // ===== GEMM2: emb += w2t(A) * h_relu(B), reads buf1 =====
    #pragma unroll
    for (int kk = 0; kk < 8; ++kk)
      #pragma unroll
      for (int t = 0; t < 4; ++t) {
        bf8v wf = *(const bf8v*)&ldsW1[swz(t * 32 + l31, kk * 16 + h8)];
        emb[t] = __builtin_amdgcn_mfma_f32_32x32x16_bf16(wf, bB[kk], emb[t], 0, 0, 0);
      }
  } // d loop

  // ===== final LN + ReLU (registers) ; GEMM3 (buf0 = w3) ; store =====
  bf8v bB[8];
  {
    float s = 0.0f, ss = 0.0f;
    #pragma unroll
    for (int t = 0; t < 4; ++t)
      #pragma unroll
      for (int x = 0; x < 16; ++x) {
        float v = emb[t][x];
        s += v; ss += v * v;
      }
    s  += __shfl_xor(s, 32);
    ss += __shfl_xor(ss, 32);
    float mu   = s * (1.0f / 128.0f);
    float var  = ss * (1.0f / 128.0f) - mu * mu;
    float rstd = rsqrtf(var + 1e-5f);
    #pragma unroll
    for (int t = 0; t < 4; ++t)
      #pragma unroll
      for (int a = 0; a < 4; ++a) {
        f4v gv = *(const f4v*)&ldsP[P_OG + t * 32 + a * 8 + h4];
        f4v bv = *(const f4v*)&ldsP[P_OB + t * 32 + a * 8 + h4];
        #pragma unroll
        for (int r = 0; r < 4; ++r) {
          float v = (emb[t][a * 4 + r] - mu) * rstd * gv[r] + bv[r];
          emb[t][a * 4 + r] = fmaxf(v, 0.0f);
        }
      }
    pack_frag32(emb, bB);
  }

  // GEMM3 C-init = b3 (folds the final bias add)
  f16v acc[4];
  #pragma unroll
  for (int t = 0; t < 4; ++t)
    #pragma unroll
    for (int a = 0; a < 4; ++a) {
      f4v b3v = *(const f4v*)&ldsP[P_B3 + t * 32 + a * 8 + h4];
      #pragma unroll
      for (int r = 0; r < 4; ++r) acc[t][a * 4 + r] = b3v[r];
    }
  VM_SYNC0();  // w3 landed (staged at d=3, a full phase ago)

  #pragma unroll
  for (int kk = 0; kk < 8; ++kk)
    #pragma unroll
    for (int t = 0; t < 4; ++t) {
      bf8v wf = *(const bf8v*)&ldsW0[swz(t * 32 + l31, kk * 16 + h8)];
      acc[t] = __builtin_amdgcn_mfma_f32_32x32x16_bf16(wf, bB[kk], acc[t], 0, 0, 0);
    }

  #pragma unroll
  for (int t = 0; t < 4; ++t)
    #pragma unroll
    for (int a = 0; a < 4; ++a) {
      f4v o;
      #pragma unroll
      for (int r = 0; r < 4; ++r) o[r] = acc[t][a * 4 + r];
      *(f4v*)&out[(rowbase + wrow + l31) * HH + t * 32 + a * 8 + h4] = o;
    }
}

extern "C" void kernel_launch(void* const* d_in, const int* in_sizes, int n_in,
                              void* d_out, int out_size, void* d_ws, size_t ws_size,
                              hipStream_t stream) {
  const float* cont  = (const float*)d_in[0];
  const float* freqs = (const float*)d_in[1];
  const float* w1    = (const float*)d_in[2];
  const float* b1    = (const float*)d_in[3];
  const float* ln1g  = (const float*)d_in[4];
  const float* ln1b  = (const float*)d_in[5];
  const float* w2    = (const float*)d_in[6];
  const float* b2    = (const float*)d_in[7];
  const float* outg  = (const float*)d_in[8];
  const float* outb  = (const float*)d_in[9];
  const float* w3    = (const float*)d_in[10];
  const float* b3    = (const float*)d_in[11];
  float* out = (float*)d_out;

  // ws layout: w1t[65536] bf16 | w2t[65536] bf16 | w3t[16384] bf16 | w1last[512] f32
  bf16t* w1t = (bf16t*)d_ws;
  bf16t* w2t = w1t + DD * HH * HH;
  bf16t* w3t = w2t + DD * HH * HH;
  float* w1last = (float*)((char*)d_ws + (2 * DD * HH * HH + HH * HH) * sizeof(bf16t));

  prep_weights<<<(DD * FIN * HH + 255) / 256, 256, 0, stream>>>(
      w1, w2, w3, w1t, w2t, w3t, w1last);

  int n_rows = in_sizes[0] / DD;       // 131072
  int grid = n_rows / MT;              // 1024
  fourier_mlp<<<grid, 256, 0, stream>>>(
      cont, freqs, b1, ln1g, ln1b, b2, outg, outb, b3,
      w1t, w2t, w3t, w1last, out);
}

// Round 19
// 154.094 us; speedup vs baseline: 1.0194x; 1.0194x over previous
//
#include <hip/hip_runtime.h>
#include <hip/hip_bf16.h>
#include <math.h>

typedef __bf16 bf16t;
typedef __bf16 bf8v __attribute__((ext_vector_type(8)));
typedef float  f4v  __attribute__((ext_vector_type(4)));
typedef float  f16v __attribute__((ext_vector_type(16)));
typedef unsigned int u32;
typedef u32 u4v __attribute__((ext_vector_type(4)));

#define DD  4
#define FF  64
#define HH  128
#define FIN 129
#define MT  128   // rows per block; 32 rows per wave (one 32-col C tile)

#define AS1 __attribute__((address_space(1)))
#define AS3 __attribute__((address_space(3)))

// param LDS offsets (f32 elements). P_B2S holds b2 summed over d (b2 enters
// linearly before the post-sum LN, so Σ_d b2[d] folds into emb's C-init).
#define P_FREQS 0      // [4][64]
#define P_B1    256    // [4][128]
#define P_W1L   768    // [4][128]
#define P_G1    1280   // [4][128]
#define P_BB1   1792   // [4][128]
#define P_B2S   2304   // [128]
#define P_OG    2432   // [128]
#define P_OB    2560   // [128]
#define P_B3    2688   // [128]
#define P_TOT   2816   // 11.3 KB; total LDS = 64 KB (2 bufs) + 11.3 KB

// XOR-swizzled LDS index: element [row][k] of a row-major [*][128] bf16 tile,
// 16B chunk (k>>3) XORed with (row&7) -> spread banks for ds_read_b128.
__device__ __forceinline__ int swz(int row, int k) {
  return row * HH + ((((k >> 3) ^ (row & 7)) << 3) | (k & 7));
}

// Hidden-index permutation for CONTRACTION tiles (w2, w3), 32x32x16 version.
// C-layout (m74/m101): col=lane&31, row=(reg&3)+8*(reg>>2)+4*(lane>>5).
// B slot (half h=lane>>5, elem j) at k-step kk consumes staged k-row
// g = kk*16+8h+j. Staged g holding original hidden o = g with bits 2<->3
// swapped makes the B fragment equal the lane's own C registers -> ZERO
// cross-lane shuffles (involution).
__device__ __forceinline__ int hperm32(int k) {
  return (k & ~12) | ((k & 4) << 1) | ((k & 8) >> 1);
}

// ---- weight prep: f32 -> bf16, transposed to [n][k] for fragment loads ----
// SOURCE-indexed: thread i reads w{1,2,3}[i] COALESCED and scatter-writes the
// 2B bf16 transposed element (scattered stores are fire-and-forget).
__global__ void prep_weights(const float* __restrict__ w1,
                             const float* __restrict__ w2,
                             const float* __restrict__ w3,
                             bf16t* __restrict__ w1t,
                             bf16t* __restrict__ w2t,
                             bf16t* __restrict__ w3t,
                             float* __restrict__ w1last) {
  int i = blockIdx.x * blockDim.x + threadIdx.x;
  if (i < DD * FIN * HH) {           // 66048: w1 -> w1t (k<128) | w1last (k=128)
    int n = i & 127, dk = i >> 7, k = dk % FIN, d = dk / FIN;
    float v = w1[i];
    if (k == 128) w1last[d * HH + n] = v;
    else          w1t[(d * HH + n) * HH + k] = (bf16t)v;
  }
  if (i < DD * HH * HH) {            // 65536: w2 -> w2t (k hperm32'd dest)
    int n = i & 127, k = (i >> 7) & 127, d = i >> 14;
    w2t[(d * HH + n) * HH + hperm32(k)] = (bf16t)w2[i];
  }
  if (i < HH * HH) {                 // 16384: w3 -> w3t (k hperm32'd dest)
    int n = i & 127, k = i >> 7;
    w3t[n * HH + hperm32(k)] = (bf16t)w3[i];
  }
}

// Async stage of a 128x128 bf16 [n][k] tile into swizzled LDS via
// global_load_lds (width 16). LDS dest LINEAR; XOR swizzle applied to the
// GLOBAL source chunk. Exactly 8 VMEM ops per wave.
__device__ __forceinline__ void stage_w_async(const bf16t* __restrict__ w,
                                              bf16t* __restrict__ ldsW,
                                              int tid, int wave) {
  int g0 = (tid & ~15) | ((tid & 15) ^ ((tid >> 4) & 7));
  const bf16t* src = w + g0 * 8;            // 16B source chunk (permuted)
  bf16t* dst = ldsW + wave * 64 * 8;        // wave-uniform 16B-chunk base
  #pragma unroll
  for (int j = 0; j < 8; ++j) {
    __builtin_amdgcn_global_load_lds((const AS1 void*)(src + j * 2048),
                                     (AS3 void*)(dst + j * 2048), 16, 0, 0);
  }
}

__device__ __forceinline__ u32 pack2(float a, float b) {
  union { bf16t h; unsigned short u; } ua, ub;
  ua.h = (bf16t)a; ub.h = (bf16t)b;
  return ((u32)ub.u << 16) | (u32)ua.u;
}

// Shuffle-free B-fragment pack (companion of hperm32):
// bb[kk=2t+s] element j = h[tile t][reg j+8s].
__device__ __forceinline__ void pack_frag32(const f16v (&h)[4], bf8v (&bb)[8]) {
  #pragma unroll
  for (int t = 0; t < 4; ++t)
    #pragma unroll
    for (int s = 0; s < 2; ++s) {
      u4v wv;
      wv.x = pack2(h[t][8 * s + 0], h[t][8 * s + 1]);
      wv.y = pack2(h[t][8 * s + 2], h[t][8 * s + 3]);
      wv.z = pack2(h[t][8 * s + 4], h[t][8 * s + 5]);
      wv.w = pack2(h[t][8 * s + 6], h[t][8 * s + 7]);
      union { u4v w; bf8v v; } cv;
      cv.w = wv;
      bb[2 * t + s] = cv.v;
    }
}

// Drain-then-barrier. In this schedule each drain point has ONLY the wave's
// own 8 stage-loads outstanding, issued a full compute phase earlier -> the
// vmcnt(0) wait is ~free, and the barrier doubles as the WAR fence for the
// buffer restaged right after it (all waves past it have, by program order,
// finished the GEMM that read that buffer).
#define VM_SYNC0() do {                                        \
    asm volatile("s_waitcnt vmcnt(0)" ::: "memory");           \
    __builtin_amdgcn_s_barrier();                              \
  } while (0)

__launch_bounds__(256, 2)
__global__ void fourier_mlp(
    const float* __restrict__ cont,   // [N,4]
    const float* __restrict__ freqs,  // [4,64]
    const float* __restrict__ b1,     // [4,128]
    const float* __restrict__ ln1g,
    const float* __restrict__ ln1b,
    const float* __restrict__ b2,
    const float* __restrict__ outg,   // [128]
    const float* __restrict__ outb,
    const float* __restrict__ b3,
    const bf16t* __restrict__ w1t,    // [4][128][128] bf16, [d][n][k]
    const bf16t* __restrict__ w2t,    // [4][128][128] (k hperm32'd)
    const bf16t* __restrict__ w3t,    // [128][128]    (k hperm32'd)
    const float* __restrict__ w1last, // [4][128]
    float* __restrict__ out)          // [N,128] f32
{
  __shared__ __align__(16) bf16t ldsW0[HH * HH];  // 32 KB: w1[d] / w3
  __shared__ __align__(16) bf16t ldsW1[HH * HH];  // 32 KB: w2[d]
  __shared__ __align__(16) float ldsP[P_TOT];     // 11.3 KB: small params

  const int tid  = threadIdx.x;
  const int lane = tid & 63;
  const int wave = tid >> 6;        // 0..3
  const int l31  = lane & 31;       // C col = batch row within wave slab
  const int h    = lane >> 5;       // lane half
  const int h8   = h * 8;           // A/B k sub-range base
  const int h4   = h * 4;           // C row sub-offset
  const int rowbase = blockIdx.x * MT;
  const int wrow = wave * 32;       // wave's 32-row slab

  // ---- prologue: w1[0] -> ldsW0 (async), params -> ldsP, cont -> regs ----
  f4v call = *(const f4v*)&cont[(rowbase + wrow + l31) * DD];

  stage_w_async(w1t, ldsW0, tid, wave);
  ldsP[P_FREQS + tid] = freqs[tid];
  #pragma unroll
  for (int i = 0; i < 2; ++i) {
    int j = tid + i * 256;
    ldsP[P_B1 + j]  = b1[j];
    ldsP[P_W1L + j] = w1last[j];
    ldsP[P_G1 + j]  = ln1g[j];
    ldsP[P_BB1 + j] = ln1b[j];
  }
  if (tid < 128) {
    // b2 summed over d: enters linearly before the post-sum LN
    ldsP[P_B2S + tid] = b2[tid] + b2[HH + tid] + b2[2 * HH + tid] + b2[3 * HH + tid];
    ldsP[P_OG + tid] = outg[tid];
    ldsP[P_OB + tid] = outb[tid];
    ldsP[P_B3 + tid] = b3[tid];
  }

  __syncthreads();  // full drain once: w1[0] + params + cont all ready

  // emb C-init = b2sum (folds all four per-d b2 adds)
  f16v emb[4];
  #pragma unroll
  for (int t = 0; t < 4; ++t)
    #pragma unroll
    for (int a = 0; a < 4; ++a) {
      f4v b2s = *(const f4v*)&ldsP[P_B2S + t * 32 + a * 8 + h4];
      #pragma unroll
      for (int r = 0; r < 4; ++r) emb[t][a * 4 + r] = b2s[r];
    }

  for (int d = 0; d < DD; ++d) {
    const float c = call[d];

    // GEMM1 C-init = b1 + c*w1last (VALU-only; overlaps w1[d] staging)
    f16v acc[4];
    #pragma unroll
    for (int t = 0; t < 4; ++t)
      #pragma unroll
      for (int a = 0; a < 4; ++a) {
        f4v b1v = *(const f4v*)&ldsP[P_B1 + d * HH + t * 32 + a * 8 + h4];
        f4v w1l = *(const f4v*)&ldsP[P_W1L + d * HH + t * 32 + a * 8 + h4];
        #pragma unroll
        for (int r = 0; r < 4; ++r) acc[t][a * 4 + r] = b1v[r] + c * w1l[r];
      }

    // trig B-frags: fB[kk<4] = cos block, fB[4+kk2] = sin block.
    // Slot j at step kk, half h -> feature (kk&3)*16 + h8 + j.
    bf8v fB[8];
    #pragma unroll
    for (int k2 = 0; k2 < 4; ++k2) {
      f4v f0 = *(const f4v*)&ldsP[P_FREQS + d * FF + k2 * 16 + h8];
      f4v f1 = *(const f4v*)&ldsP[P_FREQS + d * FF + k2 * 16 + h8 + 4];
      #pragma unroll
      for (int u = 0; u < 8; ++u) {
        float fv = (u < 4) ? f0[u] : f1[u - 4];
        float a = c * fv;
        float t = a - floorf(a);   // revolutions: sin/cos(2*pi*t)
        fB[k2][u]     = (bf16t)__builtin_amdgcn_cosf(t);
        fB[4 + k2][u] = (bf16t)__builtin_amdgcn_sinf(t);
      }
    }

    VM_SYNC0();  // A: w1[d] landed; all waves done GEMM2[d-1] (buf1 free)

    // w2[d] -> buf1 (WAR safe: barrier A implies GEMM2[d-1] complete).
    // Latency window = GEMM1 + epilogue.
    stage_w_async(w2t + d * HH * HH, ldsW1, tid, wave);

    // ===== GEMM1: acc[t] += w1t(A) * feat(B), reads buf0 =====
    #pragma unroll
    for (int kk = 0; kk < 8; ++kk)
      #pragma unroll
      for (int t = 0; t < 4; ++t) {
        bf8v wf = *(const bf8v*)&ldsW0[swz(t * 32 + l31, kk * 16 + h8)];
        acc[t] = __builtin_amdgcn_mfma_f32_32x32x16_bf16(wf, fB[kk], acc[t], 0, 0, 0);
      }

    // ===== epilogue: LN over hidden (bias already in acc), ReLU, pack =====
    bf8v bB[8];
    {
      float s = 0.0f, ss = 0.0f;
      #pragma unroll
      for (int t = 0; t < 4; ++t)
        #pragma unroll
        for (int x = 0; x < 16; ++x) {
          float v = acc[t][x];
          s += v; ss += v * v;
        }
      s  += __shfl_xor(s, 32);   // partner lane holds the other 16 rows/tile
      ss += __shfl_xor(ss, 32);
      float mu   = s * (1.0f / 128.0f);
      float var  = ss * (1.0f / 128.0f) - mu * mu;
      float rstd = rsqrtf(var + 1e-5f);
      #pragma unroll
      for (int t = 0; t < 4; ++t)
        #pragma unroll
        for (int a = 0; a < 4; ++a) {
          f4v gv = *(const f4v*)&ldsP[P_G1 + d * HH + t * 32 + a * 8 + h4];
          f4v bv = *(const f4v*)&ldsP[P_BB1 + d * HH + t * 32 + a * 8 + h4];
          #pragma unroll
          for (int r = 0; r < 4; ++r) {
            float v = (acc[t][a * 4 + r] - mu) * rstd * gv[r] + bv[r];
            acc[t][a * 4 + r] = fmaxf(v, 0.0f);
          }
        }
      pack_frag32(acc, bB);   // zero-shuffle (hperm32'd w2 compensates)
    }

    VM_SYNC0();  // B: w2[d] landed; all waves done GEMM1[d] (buf0 free)

    // next w1 (or w3) -> buf0 (WAR safe: barrier B implies GEMM1[d] complete).
    // Latency window = GEMM2 + next iteration's C-init/trig (or final LN).
    stage_w_async(d < 3 ? (w1t + (d + 1) * HH * HH) : w3t, ldsW0, tid, wave);

    // ===== GEMM2: emb += w2t(A) * h_relu(B), reads buf1 =====
    #pragma unroll
    for (int kk = 0; kk < 8; ++kk)
      #pragma unroll
      for (int t = 0; t < 4; ++t) {
        bf8v wf = *(const bf8v*)&ldsW1[swz(t * 32 + l31, kk * 16 + h8)];
        emb[t] = __builtin_amdgcn_mfma_f32_32x32x16_bf16(wf, bB[kk], emb[t], 0, 0, 0);
      }
  } // d loop

  // ===== final LN + ReLU (registers) ; GEMM3 (buf0 = w3) ; store =====
  bf8v bB[8];
  {
    float s = 0.0f, ss = 0.0f;
    #pragma unroll
    for (int t = 0; t < 4; ++t)
      #pragma unroll
      for (int x = 0; x < 16; ++x) {
        float v = emb[t][x];
        s += v; ss += v * v;
      }
    s  += __shfl_xor(s, 32);
    ss += __shfl_xor(ss, 32);
    float mu   = s * (1.0f / 128.0f);
    float var  = ss * (1.0f / 128.0f) - mu * mu;
    float rstd = rsqrtf(var + 1e-5f);
    #pragma unroll
    for (int t = 0; t < 4; ++t)
      #pragma unroll
      for (int a = 0; a < 4; ++a) {
        f4v gv = *(const f4v*)&ldsP[P_OG + t * 32 + a * 8 + h4];
        f4v bv = *(const f4v*)&ldsP[P_OB + t * 32 + a * 8 + h4];
        #pragma unroll
        for (int r = 0; r < 4; ++r) {
          float v = (emb[t][a * 4 + r] - mu) * rstd * gv[r] + bv[r];
          emb[t][a * 4 + r] = fmaxf(v, 0.0f);
        }
      }
    pack_frag32(emb, bB);
  }

  // GEMM3 C-init = b3 (folds the final bias add)
  f16v acc[4];
  #pragma unroll
  for (int t = 0; t < 4; ++t)
    #pragma unroll
    for (int a = 0; a < 4; ++a) {
      f4v b3v = *(const f4v*)&ldsP[P_B3 + t * 32 + a * 8 + h4];
      #pragma unroll
      for (int r = 0; r < 4; ++r) acc[t][a * 4 + r] = b3v[r];
    }
  VM_SYNC0();  // w3 landed (staged at d=3, a full phase ago)

  #pragma unroll
  for (int kk = 0; kk < 8; ++kk)
    #pragma unroll
    for (int t = 0; t < 4; ++t) {
      bf8v wf = *(const bf8v*)&ldsW0[swz(t * 32 + l31, kk * 16 + h8)];
      acc[t] = __builtin_amdgcn_mfma_f32_32x32x16_bf16(wf, bB[kk], acc[t], 0, 0, 0);
    }

  #pragma unroll
  for (int t = 0; t < 4; ++t)
    #pragma unroll
    for (int a = 0; a < 4; ++a) {
      f4v o;
      #pragma unroll
      for (int r = 0; r < 4; ++r) o[r] = acc[t][a * 4 + r];
      *(f4v*)&out[(rowbase + wrow + l31) * HH + t * 32 + a * 8 + h4] = o;
    }
}

extern "C" void kernel_launch(void* const* d_in, const int* in_sizes, int n_in,
                              void* d_out, int out_size, void* d_ws, size_t ws_size,
                              hipStream_t stream) {
  const float* cont  = (const float*)d_in[0];
  const float* freqs = (const float*)d_in[1];
  const float* w1    = (const float*)d_in[2];
  const float* b1    = (const float*)d_in[3];
  const float* ln1g  = (const float*)d_in[4];
  const float* ln1b  = (const float*)d_in[5];
  const float* w2    = (const float*)d_in[6];
  const float* b2    = (const float*)d_in[7];
  const float* outg  = (const float*)d_in[8];
  const float* outb  = (const float*)d_in[9];
  const float* w3    = (const float*)d_in[10];
  const float* b3    = (const float*)d_in[11];
  float* out = (float*)d_out;

  // ws layout: w1t[65536] bf16 | w2t[65536] bf16 | w3t[16384] bf16 | w1last[512] f32
  bf16t* w1t = (bf16t*)d_ws;
  bf16t* w2t = w1t + DD * HH * HH;
  bf16t* w3t = w2t + DD * HH * HH;
  float* w1last = (float*)((char*)d_ws + (2 * DD * HH * HH + HH * HH) * sizeof(bf16t));

  prep_weights<<<(DD * FIN * HH + 255) / 256, 256, 0, stream>>>(
      w1, w2, w3, w1t, w2t, w3t, w1last);

  int n_rows = in_sizes[0] / DD;       // 131072
  int grid = n_rows / MT;              // 1024
  fourier_mlp<<<grid, 256, 0, stream>>>(
      cont, freqs, b1, ln1g, ln1b, b2, outg, outb, b3,
      w1t, w2t, w3t, w1last, out);
}